// Round 3
// baseline (283.614 us; speedup 1.0000x reference)
//
#include <hip/hip_runtime.h>

typedef __attribute__((ext_vector_type(8))) short bf16x8;
typedef __attribute__((ext_vector_type(4))) short bf16x4;
typedef __attribute__((ext_vector_type(4))) float f32x4;
typedef __attribute__((ext_vector_type(2))) float f32x2;
typedef __attribute__((ext_vector_type(2))) unsigned u32x2;
typedef __attribute__((ext_vector_type(4))) unsigned u32x4;

#define DEVI static __device__ __forceinline__
#define AS1 __attribute__((address_space(1)))
#define AS3 __attribute__((address_space(3)))

DEVI unsigned short f2bf(float f) {
  unsigned u = __builtin_bit_cast(unsigned, f);
  return (unsigned short)((u + 0x7FFFu + ((u >> 16) & 1u)) >> 16);
}

// packed f32x2 -> bf16x2 (gfx950 v_cvt_pk_bf16_f32 when available)
DEVI unsigned pkbf(float a, float b) {
#if __has_builtin(__builtin_amdgcn_cvt_pk_bf16_f32)
  return __builtin_bit_cast(unsigned, __builtin_amdgcn_cvt_pk_bf16_f32(a, b));
#else
  return (unsigned)f2bf(a) | ((unsigned)f2bf(b) << 16);
#endif
}

DEVI float fast_exp2(float x) {
#if __has_builtin(__builtin_amdgcn_exp2f)
  return __builtin_amdgcn_exp2f(x);
#else
  return exp2f(x);
#endif
}

// async 16B global->LDS; LDS dest = uniform base + lane*16
DEVI void gl_lds16(const unsigned short* g, unsigned short* l) {
  __builtin_amdgcn_global_load_lds((const AS1 unsigned int*)g, (AS3 unsigned int*)l, 16, 0, 0);
}

// fragment-major element offset: [row-tile16][k-granule8][16 rows][8 k]
DEVI size_t frag_off(int row, int k, int KG) {
  return ((size_t)(row >> 4) * KG + (k >> 3)) * 128 + (row & 15) * 8 + (k & 7);
}

// ---------------------------------------------------------------------------
// x fp32 [32768][320] -> bf16 fragment-major xbf_fr. One thread = one 16B granule
// chunk (mt, r, g): reads 32B fp32 coalesced-in-g, writes 16B.
// ---------------------------------------------------------------------------
__global__ __launch_bounds__(256)
void k_prep(const float* __restrict__ x, unsigned short* __restrict__ xf) {
  int t = blockIdx.x * 256 + threadIdx.x;  // 1,310,720 total
  int mt = t / 640, rem = t - mt * 640;
  int r = rem / 40, g = rem - r * 40;
  const float* p = x + (size_t)(mt * 16 + r) * 320 + g * 8;
  f32x4 a = ((const f32x4*)p)[0], b = ((const f32x4*)p)[1];
  u32x4 pk = {pkbf(a[0], a[1]), pkbf(a[2], a[3]), pkbf(b[0], b[1]), pkbf(b[2], b[3])};
  *(u32x4*)(xf + ((size_t)(mt * 40 + g)) * 128 + r * 8) = pk;
}

// ---------------------------------------------------------------------------
// Weight transposes -> bf16 fragment-major. src fp32 [K][N] -> frag[n][k].
// z=0: q_w 320x320  z=1: kv_w 320x640  z=2: proj_w 320x320  z=3: sr_w 1280x320
// ---------------------------------------------------------------------------
__global__ __launch_bounds__(256)
void k_transpose_all(const float* __restrict__ q_w, const float* __restrict__ kv_w,
                     const float* __restrict__ proj_w, const float* __restrict__ sr_w,
                     unsigned short* __restrict__ Wq, unsigned short* __restrict__ Wkv,
                     unsigned short* __restrict__ Wp, unsigned short* __restrict__ Wsr) {
  const float* src; unsigned short* dst; int K, N;
  switch (blockIdx.z) {
    case 0:  src = q_w;    dst = Wq;  K = 320;  N = 320; break;
    case 1:  src = kv_w;   dst = Wkv; K = 320;  N = 640; break;
    case 2:  src = proj_w; dst = Wp;  K = 320;  N = 320; break;
    default: src = sr_w;   dst = Wsr; K = 1280; N = 320; break;
  }
  if ((int)blockIdx.x >= (K >> 5) || (int)blockIdx.y >= (N >> 5)) return;
  const int KG = K >> 3;
  __shared__ float tile[32][33];
  const int k0 = blockIdx.x * 32, n0 = blockIdx.y * 32;
  const int tx = threadIdx.x, ty = threadIdx.y;
#pragma unroll
  for (int i = 0; i < 4; i++)
    tile[ty + i * 8][tx] = src[(size_t)(k0 + ty + i * 8) * N + n0 + tx];
  __syncthreads();
#pragma unroll
  for (int i = 0; i < 4; i++) {
    int n = n0 + ty + i * 8, k = k0 + tx;
    dst[frag_off(n, k, KG)] = f2bf(tile[tx][ty + i * 8]);
  }
}

// ---------------------------------------------------------------------------
// LayerNorm: one wave per row of xc[8192][320] -> bf16 frag-major xr
// ---------------------------------------------------------------------------
__global__ __launch_bounds__(256)
void k_ln(const float* __restrict__ xc, const float* __restrict__ gam,
          const float* __restrict__ bet, unsigned short* __restrict__ xr) {
  const int row = blockIdx.x * 4 + (threadIdx.x >> 6);
  const int l = threadIdx.x & 63;
  const float* p = xc + (size_t)row * 320;
  float s = 0.f, ss = 0.f;
#pragma unroll
  for (int i = 0; i < 5; i++) { float v = p[l + 64 * i]; s += v; ss += v * v; }
#pragma unroll
  for (int o = 1; o < 64; o <<= 1) { s += __shfl_xor(s, o); ss += __shfl_xor(ss, o); }
  float mu = s * (1.f / 320.f);
  float var = ss * (1.f / 320.f) - mu * mu;
  float rstd = rsqrtf(var + 1e-5f);
  if (l < 40) {
    f32x4 a = ((const f32x4*)(p + l * 8))[0], b = ((const f32x4*)(p + l * 8))[1];
    f32x4 ga = ((const f32x4*)(gam + l * 8))[0], gb = ((const f32x4*)(gam + l * 8))[1];
    f32x4 ba = ((const f32x4*)(bet + l * 8))[0], bb = ((const f32x4*)(bet + l * 8))[1];
    f32x4 ya, yb;
#pragma unroll
    for (int j = 0; j < 4; j++) {
      ya[j] = (a[j] - mu) * rstd * ga[j] + ba[j];
      yb[j] = (b[j] - mu) * rstd * gb[j] + bb[j];
    }
    u32x4 pk = {pkbf(ya[0], ya[1]), pkbf(ya[2], ya[3]), pkbf(yb[0], yb[1]), pkbf(yb[2], yb[3])};
    *(u32x4*)(xr + ((size_t)((row >> 4) * 40 + l)) * 128 + (row & 15) * 8) = pk;
  }
}

// ---------------------------------------------------------------------------
// Register-direct GEMM (no LDS, no barriers): C[M x 64-slice] = A*W^T + bias.
// A, W in fragment-major bf16; K=320 fully unrolled; block 256 thr = 4 waves,
// wave-tile 64x64, block-tile 256x64.
// EPI: 0 = Qb bf16 [b][h][4096][64] * oscale
//      3 = fp32 out [M][320]
//      4 = KV merged: n0<320 -> Kb [b][h][1024][64]; else Vt [b][h][64][1024]
// ---------------------------------------------------------------------------
template <int EPI>
__global__ __launch_bounds__(256)
void k_gemm(const unsigned short* __restrict__ A, const unsigned short* __restrict__ W,
            const float* __restrict__ bias, void* __restrict__ outp, void* __restrict__ outp2,
            float oscale) {
  const int t = threadIdx.x, w = t >> 6, ln = t & 63, lr = ln & 15, lq = ln >> 4;
  const int m0 = blockIdx.x * 256, n0 = blockIdx.y * 64;
  const unsigned short* Ab = A + ((size_t)((m0 >> 4) + w * 4) * 40 + lq) * 128 + lr * 8;
  const unsigned short* Bb = W + ((size_t)(n0 >> 4) * 40 + lq) * 128 + lr * 8;

  f32x4 acc[4][4];
#pragma unroll
  for (int i = 0; i < 4; i++)
#pragma unroll
    for (int j = 0; j < 4; j++) acc[i][j] = (f32x4){0.f, 0.f, 0.f, 0.f};

#pragma unroll
  for (int ks = 0; ks < 10; ks++) {
    bf16x8 af[4], bf[4];
#pragma unroll
    for (int mi = 0; mi < 4; mi++)
      af[mi] = *(const bf16x8*)(Ab + ((size_t)mi * 40 + ks * 4) * 128);
#pragma unroll
    for (int ni = 0; ni < 4; ni++)
      bf[ni] = *(const bf16x8*)(Bb + ((size_t)ni * 40 + ks * 4) * 128);
#pragma unroll
    for (int mi = 0; mi < 4; mi++)
#pragma unroll
      for (int ni = 0; ni < 4; ni++)
        acc[mi][ni] =
            __builtin_amdgcn_mfma_f32_16x16x32_bf16(af[mi], bf[ni], acc[mi][ni], 0, 0, 0);
  }

  if (EPI == 0) {
    unsigned short* out = (unsigned short*)outp;
    const int h = n0 >> 6;
#pragma unroll
    for (int mi = 0; mi < 4; mi++)
#pragma unroll
      for (int ni = 0; ni < 4; ni++)
#pragma unroll
        for (int rr = 0; rr < 4; rr++) {
          int gm = m0 + w * 64 + mi * 16 + lq * 4 + rr;
          int b = gm >> 12, n = gm & 4095, d = ni * 16 + lr;
          out[((size_t)(b * 5 + h) << 18) + ((size_t)n << 6) + d] =
              f2bf((acc[mi][ni][rr] + bias[n0 + d]) * oscale);
        }
  } else if (EPI == 3) {
    float* out = (float*)outp;
#pragma unroll
    for (int mi = 0; mi < 4; mi++)
#pragma unroll
      for (int ni = 0; ni < 4; ni++)
#pragma unroll
        for (int rr = 0; rr < 4; rr++) {
          int gm = m0 + w * 64 + mi * 16 + lq * 4 + rr;
          int gc = n0 + ni * 16 + lr;
          out[(size_t)gm * 320 + gc] = acc[mi][ni][rr] + bias[gc];
        }
  } else {  // EPI == 4
    if (n0 < 320) {  // K epilogue
      unsigned short* out = (unsigned short*)outp;
      const int h = n0 >> 6;
#pragma unroll
      for (int mi = 0; mi < 4; mi++)
#pragma unroll
        for (int ni = 0; ni < 4; ni++)
#pragma unroll
          for (int rr = 0; rr < 4; rr++) {
            int gm = m0 + w * 64 + mi * 16 + lq * 4 + rr;
            int b = gm >> 10, mm = gm & 1023, d = ni * 16 + lr;
            out[((size_t)(b * 5 + h) << 16) + ((size_t)mm << 6) + d] =
                f2bf(acc[mi][ni][rr] + bias[n0 + d]);
          }
    } else {  // V epilogue: transpose bounce -> [b][h][64][1024]
      unsigned short* out = (unsigned short*)outp2;
      const int h = (n0 - 320) >> 6;
      __shared__ __align__(16) unsigned short Tl[64 * 264];
#pragma unroll
      for (int mi = 0; mi < 4; mi++)
#pragma unroll
        for (int ni = 0; ni < 4; ni++)
#pragma unroll
          for (int rr = 0; rr < 4; rr++) {
            int ml = w * 64 + mi * 16 + lq * 4 + rr;
            int d = ni * 16 + lr;
            Tl[d * 264 + ml] = f2bf(acc[mi][ni][rr] + bias[n0 + d]);
          }
      __syncthreads();
      const int b = m0 >> 10, mm0 = m0 & 1023;
#pragma unroll
      for (int i = 0; i < 8; i++) {
        int ch = t + 256 * i, d = ch >> 5, g = ch & 31;
        *(bf16x8*)(out + ((size_t)(b * 5 + h) << 16) + d * 1024 + mm0 + g * 8) =
            *(const bf16x8*)(Tl + d * 264 + g * 8);
      }
    }
  }
}

// ---------------------------------------------------------------------------
// SR conv as register GEMM: xc[8192][320] = gather(x fp32)[8192][1280]*Wsr + b
// ---------------------------------------------------------------------------
__global__ __launch_bounds__(256)
void k_conv(const float* __restrict__ x, const unsigned short* __restrict__ W,
            const float* __restrict__ sr_b, float* __restrict__ xc) {
  const int t = threadIdx.x, w = t >> 6, ln = t & 63, lr = ln & 15, lq = ln >> 4;
  const int m0 = blockIdx.x * 256, n0 = blockIdx.y * 64;
  int rowb[4];
#pragma unroll
  for (int mi = 0; mi < 4; mi++) {
    int gm = m0 + w * 64 + mi * 16 + lr;
    int b = gm >> 10, pix = gm & 1023, oy = pix >> 5, ox = pix & 31;
    rowb[mi] = ((b * 64 + 2 * oy) * 64 + 2 * ox) * 320;
  }
  const unsigned short* Bb = W + ((size_t)(n0 >> 4) * 160 + lq) * 128 + lr * 8;

  f32x4 acc[4][4];
#pragma unroll
  for (int i = 0; i < 4; i++)
#pragma unroll
    for (int j = 0; j < 4; j++) acc[i][j] = (f32x4){0.f, 0.f, 0.f, 0.f};

#pragma unroll
  for (int kh = 0; kh < 2; kh++)
#pragma unroll
    for (int kw = 0; kw < 2; kw++) {
      const int seg = (kh * 64 + kw) * 320;
      const int gseg = (kh * 2 + kw) * 40;
#pragma unroll
      for (int ci = 0; ci < 10; ci++) {
        bf16x8 af[4], bf[4];
#pragma unroll
        for (int mi = 0; mi < 4; mi++) {
          const float* p = x + rowb[mi] + seg + ci * 32 + lq * 8;
          f32x4 a = ((const f32x4*)p)[0], b2 = ((const f32x4*)p)[1];
          u32x4 pk = {pkbf(a[0], a[1]), pkbf(a[2], a[3]), pkbf(b2[0], b2[1]), pkbf(b2[2], b2[3])};
          af[mi] = __builtin_bit_cast(bf16x8, pk);
        }
#pragma unroll
        for (int ni = 0; ni < 4; ni++)
          bf[ni] = *(const bf16x8*)(Bb + ((size_t)ni * 160 + gseg + ci * 4) * 128);
#pragma unroll
        for (int mi = 0; mi < 4; mi++)
#pragma unroll
          for (int ni = 0; ni < 4; ni++)
            acc[mi][ni] =
                __builtin_amdgcn_mfma_f32_16x16x32_bf16(af[mi], bf[ni], acc[mi][ni], 0, 0, 0);
      }
    }
#pragma unroll
  for (int mi = 0; mi < 4; mi++)
#pragma unroll
    for (int ni = 0; ni < 4; ni++)
#pragma unroll
      for (int rr = 0; rr < 4; rr++) {
        int gm = m0 + w * 64 + mi * 16 + lq * 4 + rr;
        int gc = n0 + ni * 16 + lr;
        xc[(size_t)gm * 320 + gc] = acc[mi][ni][rr] + sr_b[gc];
      }
}

// ---------------------------------------------------------------------------
// Attention. S^T = K*Q^T -> P^T in C-layout; PV fuses two 16-kv P-tiles into
// one 16x16x32 MFMA via the kv permutation kappa(lq,j)=(2t+(j>>2))*16+lq*4+(j&3).
// Output written fragment-major for the proj GEMM.
// ---------------------------------------------------------------------------
__global__ __launch_bounds__(256)
void k_attn(const unsigned short* __restrict__ Qb, const unsigned short* __restrict__ Kb,
            const unsigned short* __restrict__ Vt, unsigned short* __restrict__ AO) {
  __shared__ __align__(16) unsigned char smem[16384];
  unsigned short* KL = (unsigned short*)smem;  // [64 kv][8 gran] swizzled
  unsigned short* VL = KL + 4096;              // [64 d][8 gran over kv] swizzled
  const int t = threadIdx.x, w = t >> 6, ln = t & 63, lr = ln & 15, lq = ln >> 4;
  const int bh = blockIdx.y;
  const int m0 = blockIdx.x * 128 + w * 32;
  const unsigned short* Qp = Qb + ((size_t)bh << 18);
  const unsigned short* Kp = Kb + ((size_t)bh << 16);
  const unsigned short* Vp = Vt + ((size_t)bh << 16);

  bf16x8 qf[2][2];
#pragma unroll
  for (int mt = 0; mt < 2; mt++)
#pragma unroll
    for (int t2 = 0; t2 < 2; t2++)
      qf[mt][t2] = *(const bf16x8*)(Qp + (size_t)(m0 + mt * 16 + lr) * 64 + t2 * 32 + lq * 8);

  f32x4 oacc[4][2];  // [dtile][mtile]
  f32x2 den2[2] = {(f32x2){0.f, 0.f}, (f32x2){0.f, 0.f}};
#pragma unroll
  for (int dt = 0; dt < 4; dt++)
#pragma unroll
    for (int mt = 0; mt < 2; mt++) oacc[dt][mt] = (f32x4){0.f, 0.f, 0.f, 0.f};

  const int rS = ln >> 3, sS = ln & 7;

  for (int c = 0; c < 16; c++) {
#pragma unroll
    for (int i = 0; i < 2; i++) {
      int r = (w * 2 + i) * 8 + rS;
      int g = sS ^ (r & 7);
      gl_lds16(Kp + (size_t)(c * 64 + r) * 64 + g * 8, KL + (w * 2 + i) * 512);
      gl_lds16(Vp + (size_t)r * 1024 + c * 64 + g * 8, VL + (w * 2 + i) * 512);
    }
    __syncthreads();

    // S^T[kv][m]
    f32x4 sacc[4][2];
#pragma unroll
    for (int kt = 0; kt < 4; kt++) {
      int kr = 16 * kt + lr;
      bf16x8 kf0 = *(const bf16x8*)(KL + kr * 64 + ((lq ^ (lr & 7)) * 8));
      bf16x8 kf1 = *(const bf16x8*)(KL + kr * 64 + (((4 + lq) ^ (lr & 7)) * 8));
#pragma unroll
      for (int mt = 0; mt < 2; mt++) {
        f32x4 s = (f32x4){0.f, 0.f, 0.f, 0.f};
        s = __builtin_amdgcn_mfma_f32_16x16x32_bf16(kf0, qf[mt][0], s, 0, 0, 0);
        s = __builtin_amdgcn_mfma_f32_16x16x32_bf16(kf1, qf[mt][1], s, 0, 0, 0);
        sacc[kt][mt] = s;
      }
    }

    // exp + pack two kt tiles per PV mfma
#pragma unroll
    for (int tp = 0; tp < 2; tp++) {
      bf16x8 pf8[2];
#pragma unroll
      for (int mt = 0; mt < 2; mt++) {
        f32x4 ea, eb;
#pragma unroll
        for (int j = 0; j < 4; j++) {
          ea[j] = fast_exp2(sacc[2 * tp][mt][j]);
          eb[j] = fast_exp2(sacc[2 * tp + 1][mt][j]);
        }
        den2[mt] += (f32x2){ea[0], ea[1]} + (f32x2){ea[2], ea[3]};
        den2[mt] += (f32x2){eb[0], eb[1]} + (f32x2){eb[2], eb[3]};
        u32x4 pk = {pkbf(ea[0], ea[1]), pkbf(ea[2], ea[3]),
                    pkbf(eb[0], eb[1]), pkbf(eb[2], eb[3])};
        pf8[mt] = __builtin_bit_cast(bf16x8, pk);
      }
#pragma unroll
      for (int dt = 0; dt < 4; dt++) {
        int vr = dt * 16 + lr;
        const unsigned short* vbase = VL + vr * 64;
        int ga = 4 * tp + (lq >> 1), gb = ga + 2;
        bf16x4 vlo = *(const bf16x4*)(vbase + (ga ^ (lr & 7)) * 8 + (lq & 1) * 4);
        bf16x4 vhi = *(const bf16x4*)(vbase + (gb ^ (lr & 7)) * 8 + (lq & 1) * 4);
        bf16x8 vf8 = {vlo[0], vlo[1], vlo[2], vlo[3], vhi[0], vhi[1], vhi[2], vhi[3]};
#pragma unroll
        for (int mt = 0; mt < 2; mt++)
          oacc[dt][mt] =
              __builtin_amdgcn_mfma_f32_16x16x32_bf16(vf8, pf8[mt], oacc[dt][mt], 0, 0, 0);
      }
    }
    __syncthreads();
  }

  float inv[2];
#pragma unroll
  for (int mt = 0; mt < 2; mt++) {
    float s = den2[mt][0] + den2[mt][1];
    s += __shfl_xor(s, 16);
    s += __shfl_xor(s, 32);
    inv[mt] = 1.f / s;
  }

  const int b = bh / 5, h = bh - b * 5;
  const int rt0 = b * 256 + (m0 >> 4);
#pragma unroll
  for (int mt = 0; mt < 2; mt++)
#pragma unroll
    for (int dt = 0; dt < 4; dt++) {
      float i0 = inv[mt];
      u32x2 pk = {pkbf(oacc[dt][mt][0] * i0, oacc[dt][mt][1] * i0),
                  pkbf(oacc[dt][mt][2] * i0, oacc[dt][mt][3] * i0)};
      int colg = h * 8 + dt * 2 + (lq >> 1);
      size_t off = ((size_t)(rt0 + mt) * 40 + colg) * 128 + lr * 8 + (lq & 1) * 4;
      *(u32x2*)(AO + off) = pk;
    }
}

// ---------------------------------------------------------------------------
extern "C" void kernel_launch(void* const* d_in, const int* in_sizes, int n_in,
                              void* d_out, int out_size, void* d_ws, size_t ws_size,
                              hipStream_t stream) {
  (void)in_sizes; (void)n_in; (void)out_size; (void)ws_size;
  const float* x      = (const float*)d_in[0];
  const float* q_w    = (const float*)d_in[1];
  const float* q_b    = (const float*)d_in[2];
  const float* kv_w   = (const float*)d_in[3];
  const float* kv_b   = (const float*)d_in[4];
  const float* sr_w   = (const float*)d_in[5];
  const float* sr_b   = (const float*)d_in[6];
  const float* ln_g   = (const float*)d_in[7];
  const float* ln_b   = (const float*)d_in[8];
  const float* proj_w = (const float*)d_in[9];
  const float* proj_b = (const float*)d_in[10];
  float* out = (float*)d_out;

  char* ws = (char*)d_ws;
  size_t off = 0;
  auto alloc = [&](size_t bytes) {
    void* p = ws + off;
    off += (bytes + 255) & ~(size_t)255;
    return p;
  };
  unsigned short* xbf_fr = (unsigned short*)alloc((size_t)32768 * 320 * 2);  // aliased by AO
  unsigned short* Qb     = (unsigned short*)alloc((size_t)32768 * 320 * 2);
  unsigned short* KbP    = (unsigned short*)alloc((size_t)40 * 65536 * 2);
  unsigned short* VtP    = (unsigned short*)alloc((size_t)40 * 65536 * 2);
  float*          xc     = (float*)alloc((size_t)8192 * 320 * 4);
  unsigned short* xr     = (unsigned short*)alloc((size_t)8192 * 320 * 2);
  unsigned short* Wq_fr  = (unsigned short*)alloc((size_t)320 * 320 * 2);
  unsigned short* Wkv_fr = (unsigned short*)alloc((size_t)640 * 320 * 2);
  unsigned short* Wp_fr  = (unsigned short*)alloc((size_t)320 * 320 * 2);
  unsigned short* Wsr_fr = (unsigned short*)alloc((size_t)320 * 1280 * 2);
  unsigned short* AO = xbf_fr;  // xbf_fr dead after Q projection

  const float S2 = 0.125f * 1.4426950408889634f;  // SCALE * log2(e)

  k_prep<<<5120, 256, 0, stream>>>(x, xbf_fr);
  k_transpose_all<<<dim3(40, 20, 4), dim3(32, 8), 0, stream>>>(
      q_w, kv_w, proj_w, sr_w, Wq_fr, Wkv_fr, Wp_fr, Wsr_fr);

  k_conv<<<dim3(32, 5), 256, 0, stream>>>(x, Wsr_fr, sr_b, xc);
  k_ln<<<2048, 256, 0, stream>>>(xc, ln_g, ln_b, xr);
  k_gemm<0><<<dim3(128, 5), 256, 0, stream>>>(xbf_fr, Wq_fr, q_b, Qb, nullptr, S2);
  k_gemm<4><<<dim3(32, 10), 256, 0, stream>>>(xr, Wkv_fr, kv_b, KbP, VtP, 1.f);
  k_attn<<<dim3(32, 40), 256, 0, stream>>>(Qb, KbP, VtP, AO);
  k_gemm<3><<<dim3(128, 5), 256, 0, stream>>>(AO, Wp_fr, proj_b, out, nullptr, 1.f);
}

// Round 4
// 233.072 us; speedup vs baseline: 1.2169x; 1.2169x over previous
//
#include <hip/hip_runtime.h>

typedef __attribute__((ext_vector_type(8))) short bf16x8;
typedef __attribute__((ext_vector_type(4))) short bf16x4;
typedef __attribute__((ext_vector_type(4))) float f32x4;
typedef __attribute__((ext_vector_type(2))) float f32x2;
typedef __attribute__((ext_vector_type(2))) unsigned u32x2;
typedef __attribute__((ext_vector_type(4))) unsigned u32x4;

#define DEVI static __device__ __forceinline__
#define AS1 __attribute__((address_space(1)))
#define AS3 __attribute__((address_space(3)))

DEVI unsigned short f2bf(float f) {
  unsigned u = __builtin_bit_cast(unsigned, f);
  return (unsigned short)((u + 0x7FFFu + ((u >> 16) & 1u)) >> 16);
}

DEVI unsigned pkbf(float a, float b) {
#if __has_builtin(__builtin_amdgcn_cvt_pk_bf16_f32)
  return __builtin_bit_cast(unsigned, __builtin_amdgcn_cvt_pk_bf16_f32(a, b));
#else
  return (unsigned)f2bf(a) | ((unsigned)f2bf(b) << 16);
#endif
}

DEVI float fast_exp2(float x) {
#if __has_builtin(__builtin_amdgcn_exp2f)
  return __builtin_amdgcn_exp2f(x);
#else
  return exp2f(x);
#endif
}

// async 16B global->LDS; LDS dest = uniform base + lane*16
DEVI void gl_lds16(const unsigned short* g, unsigned short* l) {
  __builtin_amdgcn_global_load_lds((const AS1 unsigned int*)g, (AS3 unsigned int*)l, 16, 0, 0);
}

// fragment-major element offset: [row-tile16][k-granule8][16 rows][8 k]
DEVI size_t frag_off(int row, int k, int KG) {
  return ((size_t)(row >> 4) * KG + (k >> 3)) * 128 + (row & 15) * 8 + (k & 7);
}

// ---------------------------------------------------------------------------
// x fp32 [32768][320] -> bf16 fragment-major, fully coalesced via LDS bounce.
// Block = 64 rows (4 row-tiles, 40 KB LDS, XOR-swizzled granules).
// ---------------------------------------------------------------------------
__global__ __launch_bounds__(256)
void k_prep(const float* __restrict__ x, unsigned short* __restrict__ xf) {
  __shared__ __align__(16) unsigned short L[20480];
  const int t = threadIdx.x;
  const size_t base = (size_t)blockIdx.x * 64 * 320;
#pragma unroll
  for (int i = 0; i < 10; i++) {
    int c = i * 256 + t;  // 16B granule in row-major order: r = c/40, g = c%40
    const float* p = x + base + (size_t)c * 8;
    f32x4 a = ((const f32x4*)p)[0], b = ((const f32x4*)p)[1];
    u32x4 pk = {pkbf(a[0], a[1]), pkbf(a[2], a[3]), pkbf(b[0], b[1]), pkbf(b[2], b[3])};
    int r = c / 40, g = c - r * 40;
    int gidx = ((r >> 4) * 40 + g) * 16 + (r & 15);
    int sidx = gidx ^ ((gidx >> 4) & 7);
    *(u32x4*)(L + sidx * 8) = pk;
  }
  __syncthreads();
  unsigned short* outb = xf + base;  // block's frag-region is contiguous
#pragma unroll
  for (int i = 0; i < 10; i++) {
    int o = i * 256 + t;
    int sidx = o ^ ((o >> 4) & 7);
    *(u32x4*)(outb + (size_t)o * 8) = *(const u32x4*)(L + sidx * 8);
  }
}

// ---------------------------------------------------------------------------
// Weight transposes -> bf16 fragment-major. src fp32 [K][N] -> frag[n][k].
// ---------------------------------------------------------------------------
__global__ __launch_bounds__(256)
void k_transpose_all(const float* __restrict__ q_w, const float* __restrict__ kv_w,
                     const float* __restrict__ proj_w, const float* __restrict__ sr_w,
                     unsigned short* __restrict__ Wq, unsigned short* __restrict__ Wkv,
                     unsigned short* __restrict__ Wp, unsigned short* __restrict__ Wsr) {
  const float* src; unsigned short* dst; int K, N;
  switch (blockIdx.z) {
    case 0:  src = q_w;    dst = Wq;  K = 320;  N = 320; break;
    case 1:  src = kv_w;   dst = Wkv; K = 320;  N = 640; break;
    case 2:  src = proj_w; dst = Wp;  K = 320;  N = 320; break;
    default: src = sr_w;   dst = Wsr; K = 1280; N = 320; break;
  }
  if ((int)blockIdx.x >= (K >> 5) || (int)blockIdx.y >= (N >> 5)) return;
  const int KG = K >> 3;
  __shared__ float tile[32][33];
  const int k0 = blockIdx.x * 32, n0 = blockIdx.y * 32;
  const int tx = threadIdx.x, ty = threadIdx.y;
#pragma unroll
  for (int i = 0; i < 4; i++)
    tile[ty + i * 8][tx] = src[(size_t)(k0 + ty + i * 8) * N + n0 + tx];
  __syncthreads();
#pragma unroll
  for (int i = 0; i < 4; i++) {
    int n = n0 + ty + i * 8, k = k0 + tx;
    dst[frag_off(n, k, KG)] = f2bf(tile[tx][ty + i * 8]);
  }
}

// ---------------------------------------------------------------------------
// LayerNorm: one wave per row of xc[8192][320] -> bf16 frag-major xr
// ---------------------------------------------------------------------------
__global__ __launch_bounds__(256)
void k_ln(const float* __restrict__ xc, const float* __restrict__ gam,
          const float* __restrict__ bet, unsigned short* __restrict__ xr) {
  const int row = blockIdx.x * 4 + (threadIdx.x >> 6);
  const int l = threadIdx.x & 63;
  const float* p = xc + (size_t)row * 320;
  float s = 0.f, ss = 0.f;
#pragma unroll
  for (int i = 0; i < 5; i++) { float v = p[l + 64 * i]; s += v; ss += v * v; }
#pragma unroll
  for (int o = 1; o < 64; o <<= 1) { s += __shfl_xor(s, o); ss += __shfl_xor(ss, o); }
  float mu = s * (1.f / 320.f);
  float var = ss * (1.f / 320.f) - mu * mu;
  float rstd = rsqrtf(var + 1e-5f);
  if (l < 40) {
    f32x4 a = ((const f32x4*)(p + l * 8))[0], b = ((const f32x4*)(p + l * 8))[1];
    f32x4 ga = ((const f32x4*)(gam + l * 8))[0], gb = ((const f32x4*)(gam + l * 8))[1];
    f32x4 ba = ((const f32x4*)(bet + l * 8))[0], bb = ((const f32x4*)(bet + l * 8))[1];
    f32x4 ya, yb;
#pragma unroll
    for (int j = 0; j < 4; j++) {
      ya[j] = (a[j] - mu) * rstd * ga[j] + ba[j];
      yb[j] = (b[j] - mu) * rstd * gb[j] + bb[j];
    }
    u32x4 pk = {pkbf(ya[0], ya[1]), pkbf(ya[2], ya[3]), pkbf(yb[0], yb[1]), pkbf(yb[2], yb[3])};
    *(u32x4*)(xr + ((size_t)((row >> 4) * 40 + l)) * 128 + (row & 15) * 8) = pk;
  }
}

// ---------------------------------------------------------------------------
// Weights-stationary GEMM: C[M x 64-slice] = A * W^T + bias.
// W slice (64 cols x 320 k, frag-major, 40 KB) staged in LDS ONCE per segment;
// K-loop is barrier-free: A fragments register-direct from frag-major global,
// B fragments from LDS. Block = 4 waves, wave-tile (MT*16) x 64.
// AK: 0 = A frag-major rows;  1 = SR-conv row-remap (NSEG=4 (kh,kw) segments)
// EPI: 0 = Qb bf16 [b][h][4096][64] * oscale   3 = fp32 out [M][320]
//      4 = KV merged: n0<320 -> Kb; else Vt [b][h][64][1024] (LDS bounce)
// ---------------------------------------------------------------------------
template <int MT, int AK, int EPI, int NSEG>
__global__ __launch_bounds__(256)
void k_gemm(const unsigned short* __restrict__ A, const unsigned short* __restrict__ W,
            const float* __restrict__ bias, void* __restrict__ outp, void* __restrict__ outp2,
            float oscale) {
  __shared__ __align__(16) unsigned short Bl[20480];  // 40 KB
  const int t = threadIdx.x, w = t >> 6, ln = t & 63, lr = ln & 15, lq = ln >> 4;
  const int m0 = blockIdx.x * (MT * 64), n0 = blockIdx.y * 64;

  f32x4 acc[MT][4];
#pragma unroll
  for (int i = 0; i < MT; i++)
#pragma unroll
    for (int j = 0; j < 4; j++) acc[i][j] = (f32x4){0.f, 0.f, 0.f, 0.f};

  // conv row-remap constants (AK==1)
  int crt[MT], crow[MT];
  if (AK == 1) {
#pragma unroll
    for (int mi = 0; mi < MT; mi++) {
      int gm = m0 + (w * MT + mi) * 16;
      int b = gm >> 10, p = gm & 1023, oy = p >> 5, ox0 = p & 31;
      crt[mi] = b * 256 + ((2 * oy) * 64 + 2 * ox0) >> 4;  // base row-tile (kh=kw=0)
      crow[mi] = 0;
      (void)crow[mi];
    }
  }

#pragma unroll
  for (int seg = 0; seg < NSEG; seg++) {
    const int kh = seg >> 1, kw = seg & 1;
    if (seg) __syncthreads();
    if (AK == 0) {
      const unsigned short* Ws = W + ((size_t)(n0 >> 4) * 40) * 128;
#pragma unroll
      for (int j = 0; j < 10; j++)
        gl_lds16(Ws + (size_t)(j * 4 + w) * 512 + ln * 8, Bl + (j * 4 + w) * 512);
    } else {
      const unsigned short* Wt = W + ((size_t)((n0 >> 4) + w) * 160 + seg * 40) * 128;
#pragma unroll
      for (int j = 0; j < 10; j++)
        gl_lds16(Wt + (size_t)j * 512 + ln * 8, Bl + w * 5120 + j * 512);
    }
    __syncthreads();

#pragma unroll
    for (int ks = 0; ks < 10; ks++) {
      bf16x8 af[MT], bfr[4];
#pragma unroll
      for (int mi = 0; mi < MT; mi++) {
        if (AK == 0) {
          af[mi] = *(const bf16x8*)(
              A + ((size_t)((m0 >> 4) + w * MT + mi) * 40 + ks * 4 + lq) * 128 + lr * 8);
        } else {
          int gm = m0 + (w * MT + mi) * 16;
          int b = gm >> 10, p = gm & 1023, oy = p >> 5, ox0 = p & 31;
          int r0 = (2 * oy + kh) * 64 + 2 * ox0 + kw;           // r0 & 15 == kw
          int brt = b * 256 + (r0 >> 4);
          af[mi] = *(const bf16x8*)(
              A + ((size_t)(brt + (lr >> 3)) * 40 + ks * 4 + lq) * 128 +
              (kw + 2 * (lr & 7)) * 8);
        }
      }
#pragma unroll
      for (int ni = 0; ni < 4; ni++)
        bfr[ni] = *(const bf16x8*)(Bl + ((ni * 40) + ks * 4 + lq) * 128 + lr * 8);
#pragma unroll
      for (int mi = 0; mi < MT; mi++)
#pragma unroll
        for (int ni = 0; ni < 4; ni++)
          acc[mi][ni] =
              __builtin_amdgcn_mfma_f32_16x16x32_bf16(af[mi], bfr[ni], acc[mi][ni], 0, 0, 0);
    }
  }

  if (EPI == 0) {  // Qb [b][h][4096][64], scaled
    unsigned short* out = (unsigned short*)outp;
    const int h = n0 >> 6;
#pragma unroll
    for (int mi = 0; mi < MT; mi++)
#pragma unroll
      for (int ni = 0; ni < 4; ni++)
#pragma unroll
        for (int rr = 0; rr < 4; rr++) {
          int gm = m0 + (w * MT + mi) * 16 + lq * 4 + rr;
          int b = gm >> 12, n = gm & 4095, d = ni * 16 + lr;
          out[((size_t)(b * 5 + h) << 18) + ((size_t)n << 6) + d] =
              f2bf((acc[mi][ni][rr] + bias[n0 + d]) * oscale);
        }
  } else if (EPI == 3) {  // fp32 [M][320]
    float* out = (float*)outp;
#pragma unroll
    for (int mi = 0; mi < MT; mi++)
#pragma unroll
      for (int ni = 0; ni < 4; ni++)
#pragma unroll
        for (int rr = 0; rr < 4; rr++) {
          int gm = m0 + (w * MT + mi) * 16 + lq * 4 + rr;
          int gc = n0 + ni * 16 + lr;
          out[(size_t)gm * 320 + gc] = acc[mi][ni][rr] + bias[gc];
        }
  } else {  // EPI == 4: KV merged
    if (n0 < 320) {  // K -> [b][h][1024][64]
      unsigned short* out = (unsigned short*)outp;
      const int h = n0 >> 6;
#pragma unroll
      for (int mi = 0; mi < MT; mi++)
#pragma unroll
        for (int ni = 0; ni < 4; ni++)
#pragma unroll
          for (int rr = 0; rr < 4; rr++) {
            int gm = m0 + (w * MT + mi) * 16 + lq * 4 + rr;
            int b = gm >> 10, mm = gm & 1023, d = ni * 16 + lr;
            out[((size_t)(b * 5 + h) << 16) + ((size_t)mm << 6) + d] =
                f2bf(acc[mi][ni][rr] + bias[n0 + d]);
          }
    } else {  // V -> [b][h][64][1024] via LDS bounce (block = 128 rows, MT=2)
      unsigned short* out = (unsigned short*)outp2;
      const int h = (n0 - 320) >> 6;
      unsigned short* Tl = (unsigned short*)Bl;  // [64][136]
      __syncthreads();
#pragma unroll
      for (int mi = 0; mi < MT; mi++)
#pragma unroll
        for (int ni = 0; ni < 4; ni++)
#pragma unroll
          for (int rr = 0; rr < 4; rr++) {
            int ml = (w * MT + mi) * 16 + lq * 4 + rr;  // 0..127
            int d = ni * 16 + lr;
            Tl[d * 136 + ml] = f2bf(acc[mi][ni][rr] + bias[n0 + d]);
          }
      __syncthreads();
      const int b = m0 >> 10, mm0 = m0 & 1023;
#pragma unroll
      for (int i = 0; i < 4; i++) {
        int ch = t + 256 * i, d = ch >> 4, g = ch & 15;
        *(bf16x8*)(out + ((size_t)(b * 5 + h) << 16) + d * 1024 + mm0 + g * 8) =
            *(const bf16x8*)(Tl + d * 136 + g * 8);
      }
    }
  }
}

// ---------------------------------------------------------------------------
// Attention, double-buffered. S^T = K*Q^T -> P^T in C-layout; PV fuses two
// 16-kv P-tiles per 16x16x32 MFMA. One barrier per 64-kv chunk; chunk c+1 is
// staged (global_load_lds) before computing chunk c.
// ---------------------------------------------------------------------------
__global__ __launch_bounds__(256)
void k_attn(const unsigned short* __restrict__ Qb, const unsigned short* __restrict__ Kb,
            const unsigned short* __restrict__ Vt, unsigned short* __restrict__ AO) {
  __shared__ __align__(16) unsigned char smem[32768];  // 2 x (K 8KB + V 8KB)
  const int t = threadIdx.x, w = t >> 6, ln = t & 63, lr = ln & 15, lq = ln >> 4;
  const int bh = blockIdx.y;
  const int m0 = blockIdx.x * 128 + w * 32;
  const unsigned short* Qp = Qb + ((size_t)bh << 18);
  const unsigned short* Kp = Kb + ((size_t)bh << 16);
  const unsigned short* Vp = Vt + ((size_t)bh << 16);

  bf16x8 qf[2][2];
#pragma unroll
  for (int mt = 0; mt < 2; mt++)
#pragma unroll
    for (int t2 = 0; t2 < 2; t2++)
      qf[mt][t2] = *(const bf16x8*)(Qp + (size_t)(m0 + mt * 16 + lr) * 64 + t2 * 32 + lq * 8);

  f32x4 oacc[4][2];
  f32x2 den2[2] = {(f32x2){0.f, 0.f}, (f32x2){0.f, 0.f}};
#pragma unroll
  for (int dt = 0; dt < 4; dt++)
#pragma unroll
    for (int mt = 0; mt < 2; mt++) oacc[dt][mt] = (f32x4){0.f, 0.f, 0.f, 0.f};

  const int rS = ln >> 3, sS = ln & 7;

  auto stage = [&](int c, int buf) {
    unsigned short* KL = (unsigned short*)(smem + buf * 16384);
    unsigned short* VL = KL + 4096;
#pragma unroll
    for (int i = 0; i < 2; i++) {
      int r = (w * 2 + i) * 8 + rS;
      int g = sS ^ (r & 7);
      gl_lds16(Kp + (size_t)(c * 64 + r) * 64 + g * 8, KL + (w * 2 + i) * 512);
      gl_lds16(Vp + (size_t)r * 1024 + c * 64 + g * 8, VL + (w * 2 + i) * 512);
    }
  };

  stage(0, 0);
  __syncthreads();

  for (int c = 0; c < 16; c++) {
    if (c < 15) stage(c + 1, (c + 1) & 1);
    const unsigned short* KL = (const unsigned short*)(smem + (c & 1) * 16384);
    const unsigned short* VL = KL + 4096;

    // S^T[kv][m]
    f32x4 sacc[4][2];
#pragma unroll
    for (int kt = 0; kt < 4; kt++) {
      int kr = 16 * kt + lr;
      bf16x8 kf0 = *(const bf16x8*)(KL + kr * 64 + ((lq ^ (lr & 7)) * 8));
      bf16x8 kf1 = *(const bf16x8*)(KL + kr * 64 + (((4 + lq) ^ (lr & 7)) * 8));
#pragma unroll
      for (int mt = 0; mt < 2; mt++) {
        f32x4 s = (f32x4){0.f, 0.f, 0.f, 0.f};
        s = __builtin_amdgcn_mfma_f32_16x16x32_bf16(kf0, qf[mt][0], s, 0, 0, 0);
        s = __builtin_amdgcn_mfma_f32_16x16x32_bf16(kf1, qf[mt][1], s, 0, 0, 0);
        sacc[kt][mt] = s;
      }
    }

    // exp + pack; two 16-kv P-tiles feed one PV mfma
#pragma unroll
    for (int tp = 0; tp < 2; tp++) {
      bf16x8 pf8[2];
#pragma unroll
      for (int mt = 0; mt < 2; mt++) {
        f32x4 ea, eb;
#pragma unroll
        for (int j = 0; j < 4; j++) {
          ea[j] = fast_exp2(sacc[2 * tp][mt][j]);
          eb[j] = fast_exp2(sacc[2 * tp + 1][mt][j]);
        }
        den2[mt] += (f32x2){ea[0], ea[1]} + (f32x2){ea[2], ea[3]};
        den2[mt] += (f32x2){eb[0], eb[1]} + (f32x2){eb[2], eb[3]};
        u32x4 pk = {pkbf(ea[0], ea[1]), pkbf(ea[2], ea[3]),
                    pkbf(eb[0], eb[1]), pkbf(eb[2], eb[3])};
        pf8[mt] = __builtin_bit_cast(bf16x8, pk);
      }
#pragma unroll
      for (int dt = 0; dt < 4; dt++) {
        int vr = dt * 16 + lr;
        const unsigned short* vbase = VL + vr * 64;
        int ga = 4 * tp + (lq >> 1), gb = ga + 2;
        bf16x4 vlo = *(const bf16x4*)(vbase + (ga ^ (lr & 7)) * 8 + (lq & 1) * 4);
        bf16x4 vhi = *(const bf16x4*)(vbase + (gb ^ (lr & 7)) * 8 + (lq & 1) * 4);
        bf16x8 vf8 = {vlo[0], vlo[1], vlo[2], vlo[3], vhi[0], vhi[1], vhi[2], vhi[3]};
#pragma unroll
        for (int mt = 0; mt < 2; mt++)
          oacc[dt][mt] =
              __builtin_amdgcn_mfma_f32_16x16x32_bf16(vf8, pf8[mt], oacc[dt][mt], 0, 0, 0);
      }
    }
    __syncthreads();
  }

  float inv[2];
#pragma unroll
  for (int mt = 0; mt < 2; mt++) {
    float s = den2[mt][0] + den2[mt][1];
    s += __shfl_xor(s, 16);
    s += __shfl_xor(s, 32);
    inv[mt] = 1.f / s;
  }

  const int b = bh / 5, h = bh - b * 5;
  const int rt0 = b * 256 + (m0 >> 4);
#pragma unroll
  for (int mt = 0; mt < 2; mt++)
#pragma unroll
    for (int dt = 0; dt < 4; dt++) {
      float i0 = inv[mt];
      u32x2 pk = {pkbf(oacc[dt][mt][0] * i0, oacc[dt][mt][1] * i0),
                  pkbf(oacc[dt][mt][2] * i0, oacc[dt][mt][3] * i0)};
      int colg = h * 8 + dt * 2 + (lq >> 1);
      size_t off = ((size_t)(rt0 + mt) * 40 + colg) * 128 + lr * 8 + (lq & 1) * 4;
      *(u32x2*)(AO + off) = pk;
    }
}

// ---------------------------------------------------------------------------
extern "C" void kernel_launch(void* const* d_in, const int* in_sizes, int n_in,
                              void* d_out, int out_size, void* d_ws, size_t ws_size,
                              hipStream_t stream) {
  (void)in_sizes; (void)n_in; (void)out_size; (void)ws_size;
  const float* x      = (const float*)d_in[0];
  const float* q_w    = (const float*)d_in[1];
  const float* q_b    = (const float*)d_in[2];
  const float* kv_w   = (const float*)d_in[3];
  const float* kv_b   = (const float*)d_in[4];
  const float* sr_w   = (const float*)d_in[5];
  const float* sr_b   = (const float*)d_in[6];
  const float* ln_g   = (const float*)d_in[7];
  const float* ln_b   = (const float*)d_in[8];
  const float* proj_w = (const float*)d_in[9];
  const float* proj_b = (const float*)d_in[10];
  float* out = (float*)d_out;

  char* ws = (char*)d_ws;
  size_t off = 0;
  auto alloc = [&](size_t bytes) {
    void* p = ws + off;
    off += (bytes + 255) & ~(size_t)255;
    return p;
  };
  unsigned short* xbf_fr = (unsigned short*)alloc((size_t)32768 * 320 * 2);  // aliased by AO
  unsigned short* Qb     = (unsigned short*)alloc((size_t)32768 * 320 * 2);
  unsigned short* KbP    = (unsigned short*)alloc((size_t)40 * 65536 * 2);
  unsigned short* VtP    = (unsigned short*)alloc((size_t)40 * 65536 * 2);
  float*          xc     = (float*)alloc((size_t)8192 * 320 * 4);
  unsigned short* xr     = (unsigned short*)alloc((size_t)8192 * 320 * 2);
  unsigned short* Wq_fr  = (unsigned short*)alloc((size_t)320 * 320 * 2);
  unsigned short* Wkv_fr = (unsigned short*)alloc((size_t)640 * 320 * 2);
  unsigned short* Wp_fr  = (unsigned short*)alloc((size_t)320 * 320 * 2);
  unsigned short* Wsr_fr = (unsigned short*)alloc((size_t)320 * 1280 * 2);
  unsigned short* AO = xbf_fr;  // xbf_fr dead after Q projection + conv

  const float S2 = 0.125f * 1.4426950408889634f;  // SCALE * log2(e)

  k_prep<<<512, 256, 0, stream>>>(x, xbf_fr);
  k_transpose_all<<<dim3(40, 20, 4), dim3(32, 8), 0, stream>>>(
      q_w, kv_w, proj_w, sr_w, Wq_fr, Wkv_fr, Wp_fr, Wsr_fr);

  // SR conv: M=8192 (MT=2 -> 128 rows/block), 4 (kh,kw) segments
  k_gemm<2, 1, 3, 4><<<dim3(64, 5), 256, 0, stream>>>(xbf_fr, Wsr_fr, sr_b, xc, nullptr, 1.f);
  k_ln<<<2048, 256, 0, stream>>>(xc, ln_g, ln_b, xr);
  k_gemm<4, 0, 0, 1><<<dim3(128, 5), 256, 0, stream>>>(xbf_fr, Wq_fr, q_b, Qb, nullptr, S2);
  k_gemm<2, 0, 4, 1><<<dim3(64, 10), 256, 0, stream>>>(xr, Wkv_fr, kv_b, KbP, VtP, 1.f);
  k_attn<<<dim3(32, 40), 256, 0, stream>>>(Qb, KbP, VtP, AO);
  k_gemm<4, 0, 3, 1><<<dim3(128, 5), 256, 0, stream>>>(AO, Wp_fr, proj_b, out, nullptr, 1.f);
}